// Round 1
// 935.214 us; speedup vs baseline: 1.0393x; 1.0393x over previous
//
#include <hip/hip_runtime.h>

typedef _Float16 f16;
typedef _Float16 h4 __attribute__((ext_vector_type(4)));
typedef _Float16 v8h __attribute__((ext_vector_type(8)));
typedef _Float16 h8 __attribute__((ext_vector_type(8)));
typedef float v4f __attribute__((ext_vector_type(4)));

#define INV_SQRT_C 0.08838834764831845f

// ---------------- conv1: 3->32, stride 1, 256x256, ReLU, NHWC fp16 out ----------------
__global__ __launch_bounds__(256) void conv1_k(const float* __restrict__ img,
    const float* __restrict__ w1, const float* __restrict__ b1, f16* __restrict__ out)
{
  const int h = blockIdx.x, b = blockIdx.y;
  const int w = threadIdx.x;
  __shared__ float sIn[3][3][258];
  const float* imgb = img + (long)b * 3 * 65536;
  for (int idx = threadIdx.x; idx < 3 * 3 * 258; idx += 256) {
    int col = idx % 258; int t2 = idx / 258; int r = t2 % 3; int c = t2 / 3;
    int ih = h - 1 + r, iw = col - 1;
    float v = 0.f;
    if (ih >= 0 && ih < 256 && iw >= 0 && iw < 256) v = imgb[c * 65536 + ih * 256 + iw];
    sIn[c][r][col] = v;
  }
  __syncthreads();
  float acc[32];
  #pragma unroll
  for (int u = 0; u < 32; u++) acc[u] = b1[u];
  for (int c = 0; c < 3; c++)
    #pragma unroll
    for (int kh = 0; kh < 3; kh++)
      #pragma unroll
      for (int kw = 0; kw < 3; kw++) {
        float v = sIn[c][kh][w + kw];
        #pragma unroll
        for (int u = 0; u < 32; u++) acc[u] = fmaf(v, w1[(u * 3 + c) * 9 + kh * 3 + kw], acc[u]);
      }
  // NHWC store: 32 contiguous f16 per thread
  h8* o8 = (h8*)(out + (((long)(b * 256 + h) * 256) + w) * 32);
  #pragma unroll
  for (int v8 = 0; v8 < 4; v8++) {
    h8 pk;
    #pragma unroll
    for (int k = 0; k < 8; k++) {
      float r = acc[v8 * 8 + k];
      pk[k] = (f16)(r > 0.f ? r : 0.f);
    }
    o8[v8] = pk;
  }
}

// ---------------- weight transforms: OIHW fp32 -> [khkw][oc][ic] fp16 ----------------
__global__ void wt2_k(const float* __restrict__ w2, f16* __restrict__ wT)
{
  int idx = blockIdx.x * 256 + threadIdx.x;          // 18432
  int ic = idx & 31, oc = (idx >> 5) & 63, khkw = idx >> 11;
  wT[idx] = (f16)w2[(oc * 32 + ic) * 9 + khkw];
}

__global__ void wt3_k(const float* __restrict__ w3, f16* __restrict__ wT)
{
  int idx = blockIdx.x * 256 + threadIdx.x;          // 73728
  int ic5 = idx & 31, oc = (idx >> 5) & 127, ch = idx >> 12;
  int khkw = ch >> 1, ich = ch & 1;
  int ic = ich * 32 + ic5;
  wT[idx] = (f16)w3[(oc * 64 + ic) * 9 + khkw];
}

// ---------------- conv2 MFMA: 32->64, stride 2, out 128x128, NHWC fp16 ----------------
__global__ __launch_bounds__(256, 4) void conv2_m(const f16* __restrict__ in,
    const f16* __restrict__ wT, const float* __restrict__ b2, f16* __restrict__ out)
{
  const int oh = blockIdx.x, b = blockIdx.y;
  const int lane = threadIdx.x & 63, wv = threadIdx.x >> 6;
  const int n15 = lane & 15, quad = lane >> 4;
  const int ow0 = wv * 32;
  v4f acc[4][2] = {};
  const int ih0 = 2 * oh - 1;
  for (int kh = 0; kh < 3; kh++) {
    int ih = ih0 + kh;
    bool ihok = (unsigned)ih < 256u;
    const f16* inrow = in + ((long)(b * 256 + (ihok ? ih : 0))) * (256 * 32);
    for (int kw = 0; kw < 3; kw++) {
      int khkw = kh * 3 + kw;
      const f16* wp = wT + khkw * 2048 + n15 * 32 + quad * 8;
      v8h a0 = *(const v8h*)(wp);
      v8h a1 = *(const v8h*)(wp + 512);
      v8h a2 = *(const v8h*)(wp + 1024);
      v8h a3 = *(const v8h*)(wp + 1536);
      v8h bf[2];
      #pragma unroll
      for (int nt = 0; nt < 2; nt++) {
        int iw = 2 * (ow0 + nt * 16 + n15) + kw - 1;
        v8h v;
        #pragma unroll
        for (int k = 0; k < 8; k++) v[k] = (f16)0.f;
        if (ihok && (unsigned)iw < 256u) v = *(const v8h*)(inrow + iw * 32 + quad * 8);
        bf[nt] = v;
      }
      acc[0][0] = __builtin_amdgcn_mfma_f32_16x16x32_f16(a0, bf[0], acc[0][0], 0, 0, 0);
      acc[0][1] = __builtin_amdgcn_mfma_f32_16x16x32_f16(a0, bf[1], acc[0][1], 0, 0, 0);
      acc[1][0] = __builtin_amdgcn_mfma_f32_16x16x32_f16(a1, bf[0], acc[1][0], 0, 0, 0);
      acc[1][1] = __builtin_amdgcn_mfma_f32_16x16x32_f16(a1, bf[1], acc[1][1], 0, 0, 0);
      acc[2][0] = __builtin_amdgcn_mfma_f32_16x16x32_f16(a2, bf[0], acc[2][0], 0, 0, 0);
      acc[2][1] = __builtin_amdgcn_mfma_f32_16x16x32_f16(a2, bf[1], acc[2][1], 0, 0, 0);
      acc[3][0] = __builtin_amdgcn_mfma_f32_16x16x32_f16(a3, bf[0], acc[3][0], 0, 0, 0);
      acc[3][1] = __builtin_amdgcn_mfma_f32_16x16x32_f16(a3, bf[1], acc[3][1], 0, 0, 0);
    }
  }
  #pragma unroll
  for (int mt = 0; mt < 4; mt++) {
    int oc0 = mt * 16 + quad * 4;
    float4 bb = *(const float4*)(b2 + oc0);
    #pragma unroll
    for (int nt = 0; nt < 2; nt++) {
      int ow = ow0 + nt * 16 + n15;
      h4 pk;
      #pragma unroll
      for (int r = 0; r < 4; r++) {
        float v = acc[mt][nt][r] + ((const float*)&bb)[r];
        pk[r] = (f16)(v > 0.f ? v : 0.f);
      }
      *(h4*)(out + (((long)(b * 128 + oh) * 128 + ow) * 64) + oc0) = pk;
    }
  }
}

// ---------------- conv3 MFMA: 64->128, stride 2, out 64x64 ----------------
__global__ __launch_bounds__(256, 4) void conv3_m(const f16* __restrict__ in,
    const f16* __restrict__ wT, const float* __restrict__ b3,
    float* __restrict__ zout, f16* __restrict__ nhwc)
{
  const int oh = blockIdx.x, b = blockIdx.y, ocg = blockIdx.z;
  const int lane = threadIdx.x & 63, wv = threadIdx.x >> 6;
  const int n15 = lane & 15, quad = lane >> 4;
  const int ow = wv * 16 + n15;
  v4f acc[4] = {};
  const int ih0 = 2 * oh - 1;
  for (int kh = 0; kh < 3; kh++) {
    int ih = ih0 + kh;
    bool ihok = (unsigned)ih < 128u;
    const f16* inrow = in + ((long)(b * 128 + (ihok ? ih : 0))) * (128 * 64);
    for (int kw = 0; kw < 3; kw++) {
      int iw = 2 * ow + kw - 1;
      bool bok = ihok && (unsigned)iw < 128u;
      const f16* bp = inrow + iw * 64 + quad * 8;
      #pragma unroll
      for (int ich = 0; ich < 2; ich++) {
        int ch = (kh * 3 + kw) * 2 + ich;
        const f16* wp = wT + ((long)(ch * 128 + ocg * 64 + n15)) * 32 + quad * 8;
        v8h a0 = *(const v8h*)(wp);
        v8h a1 = *(const v8h*)(wp + 512);
        v8h a2 = *(const v8h*)(wp + 1024);
        v8h a3 = *(const v8h*)(wp + 1536);
        v8h bf;
        #pragma unroll
        for (int k = 0; k < 8; k++) bf[k] = (f16)0.f;
        if (bok) bf = *(const v8h*)(bp + ich * 32);
        acc[0] = __builtin_amdgcn_mfma_f32_16x16x32_f16(a0, bf, acc[0], 0, 0, 0);
        acc[1] = __builtin_amdgcn_mfma_f32_16x16x32_f16(a1, bf, acc[1], 0, 0, 0);
        acc[2] = __builtin_amdgcn_mfma_f32_16x16x32_f16(a2, bf, acc[2], 0, 0, 0);
        acc[3] = __builtin_amdgcn_mfma_f32_16x16x32_f16(a3, bf, acc[3], 0, 0, 0);
      }
    }
  }
  #pragma unroll
  for (int mt = 0; mt < 4; mt++) {
    int oc0 = ocg * 64 + mt * 16 + quad * 4;
    float4 bb = *(const float4*)(b3 + oc0);
    float rv[4];
    #pragma unroll
    for (int r = 0; r < 4; r++) {
      float v = acc[mt][r] + ((const float*)&bb)[r];
      rv[r] = v > 0.f ? v : 0.f;
    }
    #pragma unroll
    for (int r = 0; r < 4; r++)
      zout[(((long)(b * 128 + oc0 + r) * 64 + oh) * 64) + ow] = rv[r];
    h4 pk;
    #pragma unroll
    for (int r = 0; r < 4; r++) pk[r] = (f16)rv[r];
    *(h4*)(nhwc + (((long)(b * 64 + oh) * 64 + ow) * 128) + oc0) = pk;
  }
}

// ---------------- local correlation via MFMA: K=13, C=128 ----------------
// Band matmul: per (b,h) block, 4 waves each own a 16-wide w strip.
// For each ki: S[w, wq] = dot(z_t[h,w,:], z_t1[h+ki-6,wq,:]) for wq in the
// 28-col band [w0-6, w0+21], computed as 2 MFMA 16x16 tiles x 4 K-steps.
// Outputs routed through a tiny LDS tile for coalesced stores; per-(ki,kj)
// row sums fused via wave shuffle into a partial buffer for h_t.
__global__ __launch_bounds__(256) void corr_m(const f16* __restrict__ zt,
    const f16* __restrict__ zt1, float* __restrict__ corr, float* __restrict__ part)
{
  const int h = blockIdx.x, b = blockIdx.y;
  const int lane = threadIdx.x & 63, wv = threadIdx.x >> 6;
  const int n15 = lane & 15, quad = lane >> 4;
  const int w0 = wv * 16;
  __shared__ float sC[64][17];

  // A fragments: z_t row h, positions w0+n15, channel chunk quad*8 + ks*32
  const f16* arow = zt + (((long)(b * 64 + h) * 64 + (w0 + n15)) * 128) + quad * 8;
  v8h A[4];
  #pragma unroll
  for (int ks = 0; ks < 4; ks++) A[ks] = *(const v8h*)(arow + ks * 32);

  float* cb = corr + (long)b * 169 * 4096 + h * 64;

  const int q4r0 = quad * 4;
  const int wq0 = w0 - 6 + n15;   // tile 0 column position
  const int wq1 = w0 + 10 + n15;  // tile 1 column position
  const bool ok0 = (unsigned)wq0 < 64u;
  const bool ok1 = (unsigned)wq1 < 64u;

  for (int ki = 0; ki < 13; ki++) {
    int row = h + ki - 6;
    bool rok = (unsigned)row < 64u;
    v4f acc0 = {}, acc1 = {};
    if (rok) {
      const f16* brow = zt1 + ((long)(b * 64 + row) * 64) * 128;
      const f16* bp0 = brow + (long)wq0 * 128 + quad * 8;
      const f16* bp1 = brow + (long)wq1 * 128 + quad * 8;
      #pragma unroll
      for (int ks = 0; ks < 4; ks++) {
        v8h b0, b1;
        #pragma unroll
        for (int k = 0; k < 8; k++) { b0[k] = (f16)0.f; b1[k] = (f16)0.f; }
        if (ok0) b0 = *(const v8h*)(bp0 + ks * 32);
        if (ok1) b1 = *(const v8h*)(bp1 + ks * 32);
        acc0 = __builtin_amdgcn_mfma_f32_16x16x32_f16(A[ks], b0, acc0, 0, 0, 0);
        acc1 = __builtin_amdgcn_mfma_f32_16x16x32_f16(A[ks], b1, acc1, 0, 0, 0);
      }
    }
    __syncthreads();   // protect sC readers of previous ki
    // scatter: lane (quad,n15) holds D[q4r0+r][n15]; kj = wq - w + 6.
    // Every (w, kj in [0,13)) is written by exactly one (tile, r) (zeros if !rok).
    #pragma unroll
    for (int r = 0; r < 4; r++) {
      int q4r = q4r0 + r;
      int w = w0 + q4r;
      int kj0 = n15 - q4r;            // tile0
      if (kj0 >= 0 && kj0 < 13) sC[w][kj0] = acc0[r] * INV_SQRT_C;
      int kj1 = kj0 + 16;             // tile1 (always >= 1)
      if (kj1 < 13) sC[w][kj1] = acc1[r] * INV_SQRT_C;
    }
    __syncthreads();
    // coalesced store + fused row-sum (lane index == w within each wave)
    for (int idx = threadIdx.x; idx < 832; idx += 256) {
      int w = idx & 63, kj = idx >> 6;
      float v = sC[w][kj];
      cb[(long)(ki * 13 + kj) * 4096 + w] = v;
      #pragma unroll
      for (int off = 32; off > 0; off >>= 1) v += __shfl_down(v, off, 64);
      if (lane == 0) part[(long)(ki * 13 + kj) * 2048 + b * 64 + h] = v;
    }
  }
}

// ---------------- h_t: reduce partial row sums over h ----------------
// part layout: [o][b*64+h], o in [0,169)
__global__ __launch_bounds__(256) void ht2_k(const float* __restrict__ part,
                                             float* __restrict__ ht)
{
  int o = blockIdx.x;
  int t = threadIdx.x;
  int b = t >> 3, s = t & 7;
  const float* p = part + (long)o * 2048 + b * 64 + s * 8;
  float v = 0.f;
  #pragma unroll
  for (int i = 0; i < 8; i++) v += p[i];
  #pragma unroll
  for (int off = 4; off > 0; off >>= 1) v += __shfl_down(v, off, 8);
  if (s == 0) ht[b * 169 + o] = v * (1.f / 4096.f);
}

// ---------------- pred: h_t @ w_head.T + b_head ----------------
__global__ void pred_k(const float* __restrict__ ht, const float* __restrict__ wh,
                       const float* __restrict__ bh, float* __restrict__ pred)
{
  int t = threadIdx.x;
  int b = t >> 1, j = t & 1;
  float s = bh[j];
  for (int o = 0; o < 169; o++) s = fmaf(ht[b * 169 + o], wh[j * 169 + o], s);
  pred[b * 2 + j] = s;
}

extern "C" void kernel_launch(void* const* d_in, const int* in_sizes, int n_in,
                              void* d_out, int out_size, void* d_ws, size_t ws_size,
                              hipStream_t stream)
{
  (void)in_sizes; (void)n_in; (void)out_size; (void)ws_size;
  const float* img_t  = (const float*)d_in[0];
  const float* img_t1 = (const float*)d_in[1];
  const float* w1 = (const float*)d_in[2];
  const float* b1 = (const float*)d_in[3];
  const float* w2 = (const float*)d_in[4];
  const float* b2 = (const float*)d_in[5];
  const float* w3 = (const float*)d_in[6];
  const float* b3 = (const float*)d_in[7];
  const float* wh = (const float*)d_in[8];
  const float* bh = (const float*)d_in[9];
  float* out = (float*)d_out;

  // workspace layout (fp16 intermediates, 256 MiB total)
  char* ws = (char*)d_ws;
  f16* bufA = (f16*)ws;                       // conv1 out NHWC: 128 MiB (free after conv2)
  f16* bufB = (f16*)(ws + 134217728L);        // conv2 out NHWC:  64 MiB
  f16* nhT  = (f16*)(ws + 201326592L);        // z_t  NHWC fp16:  32 MiB
  f16* nhT1 = (f16*)(ws + 234881024L);        // z_t1 NHWC fp16:  32 MiB
  float* part = (float*)ws;                   // 169*2048*4 = 1.38 MiB, reuses bufA
                                              // region (convs complete before corr)

  const long OUT_ZT   = 64;
  const long OUT_ZT1  = OUT_ZT + 16777216L;
  const long OUT_CORR = OUT_ZT1 + 16777216L;
  const long OUT_HT   = OUT_CORR + 22151168L;

  // transposed weights live in the (not-yet-written) corr region of d_out;
  // corr_m fully overwrites this region afterwards.
  f16* wT2 = (f16*)(out + OUT_CORR);          // 18432 f16 = 36 KiB
  f16* wT3 = wT2 + 18432;                     // 73728 f16 = 144 KiB

  wt2_k<<<72, 256, 0, stream>>>(w2, wT2);
  wt3_k<<<288, 256, 0, stream>>>(w3, wT3);

  for (int img = 0; img < 2; img++) {
    const float* src = img ? img_t1 : img_t;
    float* zdst = out + (img ? OUT_ZT1 : OUT_ZT);
    f16* nh = img ? nhT1 : nhT;
    conv1_k<<<dim3(256, 32), 256, 0, stream>>>(src, w1, b1, bufA);
    conv2_m<<<dim3(128, 32), 256, 0, stream>>>(bufA, wT2, b2, bufB);
    conv3_m<<<dim3(64, 32, 2), 256, 0, stream>>>(bufB, wT3, b3, zdst, nh);
  }
  corr_m<<<dim3(64, 32), 256, 0, stream>>>(nhT, nhT1, out + OUT_CORR, part);
  ht2_k<<<169, 256, 0, stream>>>(part, out + OUT_HT);
  pred_k<<<1, 64, 0, stream>>>(out + OUT_HT, wh, bh, out);
}

// Round 2
// 860.606 us; speedup vs baseline: 1.1293x; 1.0867x over previous
//
#include <hip/hip_runtime.h>

typedef _Float16 f16;
typedef _Float16 h4 __attribute__((ext_vector_type(4)));
typedef _Float16 v8h __attribute__((ext_vector_type(8)));
typedef _Float16 h8 __attribute__((ext_vector_type(8)));
typedef float v4f __attribute__((ext_vector_type(4)));

#define INV_SQRT_C 0.08838834764831845f

// ---------------- weight transforms: OIHW fp32 -> [khkw][oc][ic] fp16 ----------------
__global__ void wt2_k(const float* __restrict__ w2, f16* __restrict__ wT)
{
  int idx = blockIdx.x * 256 + threadIdx.x;          // 18432
  int ic = idx & 31, oc = (idx >> 5) & 63, khkw = idx >> 11;
  wT[idx] = (f16)w2[(oc * 32 + ic) * 9 + khkw];
}

__global__ void wt3_k(const float* __restrict__ w3, f16* __restrict__ wT)
{
  int idx = blockIdx.x * 256 + threadIdx.x;          // 73728
  int ic5 = idx & 31, oc = (idx >> 5) & 127, ch = idx >> 12;
  int khkw = ch >> 1, ich = ch & 1;
  int ic = ich * 32 + ic5;
  wT[idx] = (f16)w3[(oc * 64 + ic) * 9 + khkw];
}

// ---------------- fused conv1 (3->32, s1) + conv2 MFMA (32->64, s2) ----------------
// grid (128 oh, 2 ow-half, 32 b); block 256 = 4 waves, each wave 16 ow x 64 oc.
// conv1 computed into LDS (fp16, same rounding as old bufA path); chunk index
// XOR-swizzled with (ci>>1)&3 so the stride-2 ds_read_b128 B-frag reads spread
// over 16 banks instead of 4 (16-way -> 2-way).
__global__ __launch_bounds__(256, 4) void conv12_m(const float* __restrict__ img,
    const float* __restrict__ w1, const float* __restrict__ b1,
    const f16* __restrict__ wT, const float* __restrict__ b2, f16* __restrict__ out)
{
  const int oh = blockIdx.x, g = blockIdx.y, b = blockIdx.z;
  const int tid = threadIdx.x;
  const int lane = tid & 63, wv = tid >> 6;
  const int n15 = lane & 15, quad = lane >> 4;

  __shared__ float sImg[3][5][134];
  __shared__ f16 sA[3 * 132 * 32];

  const int OW0 = g * 64;
  const int ibase = 2 * OW0 - 2;   // img col of sImg col 0
  const int ihb = 2 * oh - 2;      // img row of sImg row 0
  const float* imgb = img + (long)b * 3 * 65536;

  // stage img tile: 3 ch x 5 rows x 134 cols (zero-padded at borders)
  for (int idx = tid; idx < 3 * 5 * 134; idx += 256) {
    int col = idx % 134; int t2 = idx / 134; int r = t2 % 5; int c = t2 / 5;
    int ih = ihb + r, iw = ibase + col;
    float v = 0.f;
    if ((unsigned)ih < 256u && (unsigned)iw < 256u) v = imgb[c * 65536 + ih * 256 + iw];
    sImg[c][r][col] = v;
  }
  __syncthreads();

  // conv1: 387 pixels = 3 rows (y = 2oh-1+yr) x 129 cols (iw = 2*OW0-1+ci), 32 oc each
  for (int i = 0; i < 2; i++) {
    int p = tid + i * 256;
    if (p < 387) {
      int yr = (p >= 258) ? 2 : (p >= 129 ? 1 : 0);
      int ci = p - yr * 129;
      int y = 2 * oh - 1 + yr;
      int iw = ibase + 1 + ci;
      int s = (ci >> 1) & 3;
      f16* ap = &sA[(yr * 132 + ci) * 32];
      if ((unsigned)y < 256u && (unsigned)iw < 256u) {
        float acc[32];
        #pragma unroll
        for (int u = 0; u < 32; u++) acc[u] = b1[u];
        for (int c = 0; c < 3; c++)
          #pragma unroll
          for (int kh = 0; kh < 3; kh++)
            #pragma unroll
            for (int kw = 0; kw < 3; kw++) {
              float v = sImg[c][yr + kh][ci + kw];
              #pragma unroll
              for (int u = 0; u < 32; u++)
                acc[u] = fmaf(v, w1[(u * 3 + c) * 9 + kh * 3 + kw], acc[u]);
            }
        #pragma unroll
        for (int k = 0; k < 4; k++) {
          h8 pk;
          #pragma unroll
          for (int e = 0; e < 8; e++) {
            float r = acc[k * 8 + e];
            pk[e] = (f16)(r > 0.f ? r : 0.f);
          }
          *(h8*)(ap + ((k ^ s) << 3)) = pk;
        }
      } else {
        h8 z;
        #pragma unroll
        for (int e = 0; e < 8; e++) z[e] = (f16)0.f;
        #pragma unroll
        for (int k = 0; k < 4; k++) *(h8*)(ap + ((k ^ s) << 3)) = z;
      }
    }
  }
  __syncthreads();

  // conv2 MFMA from LDS
  v4f acc[4] = {};
  for (int kh = 0; kh < 3; kh++) {
    for (int kw = 0; kw < 3; kw++) {
      int khkw = kh * 3 + kw;
      const f16* wp = wT + khkw * 2048 + n15 * 32 + quad * 8;
      v8h a0 = *(const v8h*)(wp);
      v8h a1 = *(const v8h*)(wp + 512);
      v8h a2 = *(const v8h*)(wp + 1024);
      v8h a3 = *(const v8h*)(wp + 1536);
      int ci = 32 * wv + 2 * n15 + kw;
      v8h bf = *(const v8h*)&sA[(kh * 132 + ci) * 32 + ((quad ^ ((ci >> 1) & 3)) << 3)];
      acc[0] = __builtin_amdgcn_mfma_f32_16x16x32_f16(a0, bf, acc[0], 0, 0, 0);
      acc[1] = __builtin_amdgcn_mfma_f32_16x16x32_f16(a1, bf, acc[1], 0, 0, 0);
      acc[2] = __builtin_amdgcn_mfma_f32_16x16x32_f16(a2, bf, acc[2], 0, 0, 0);
      acc[3] = __builtin_amdgcn_mfma_f32_16x16x32_f16(a3, bf, acc[3], 0, 0, 0);
    }
  }
  const int ow = OW0 + wv * 16 + n15;
  #pragma unroll
  for (int mt = 0; mt < 4; mt++) {
    int oc0 = mt * 16 + quad * 4;
    float4 bb = *(const float4*)(b2 + oc0);
    h4 pk;
    #pragma unroll
    for (int r = 0; r < 4; r++) {
      float v = acc[mt][r] + ((const float*)&bb)[r];
      pk[r] = (f16)(v > 0.f ? v : 0.f);
    }
    *(h4*)(out + (((long)(b * 128 + oh) * 128 + ow) * 64) + oc0) = pk;
  }
}

// ---------------- conv3 MFMA: 64->128, stride 2, out 64x64 ----------------
__global__ __launch_bounds__(256, 4) void conv3_m(const f16* __restrict__ in,
    const f16* __restrict__ wT, const float* __restrict__ b3,
    float* __restrict__ zout, f16* __restrict__ nhwc)
{
  const int oh = blockIdx.x, b = blockIdx.y, ocg = blockIdx.z;
  const int lane = threadIdx.x & 63, wv = threadIdx.x >> 6;
  const int n15 = lane & 15, quad = lane >> 4;
  const int ow = wv * 16 + n15;
  v4f acc[4] = {};
  const int ih0 = 2 * oh - 1;
  for (int kh = 0; kh < 3; kh++) {
    int ih = ih0 + kh;
    bool ihok = (unsigned)ih < 128u;
    const f16* inrow = in + ((long)(b * 128 + (ihok ? ih : 0))) * (128 * 64);
    for (int kw = 0; kw < 3; kw++) {
      int iw = 2 * ow + kw - 1;
      bool bok = ihok && (unsigned)iw < 128u;
      const f16* bp = inrow + iw * 64 + quad * 8;
      #pragma unroll
      for (int ich = 0; ich < 2; ich++) {
        int ch = (kh * 3 + kw) * 2 + ich;
        const f16* wp = wT + ((long)(ch * 128 + ocg * 64 + n15)) * 32 + quad * 8;
        v8h a0 = *(const v8h*)(wp);
        v8h a1 = *(const v8h*)(wp + 512);
        v8h a2 = *(const v8h*)(wp + 1024);
        v8h a3 = *(const v8h*)(wp + 1536);
        v8h bf;
        #pragma unroll
        for (int k = 0; k < 8; k++) bf[k] = (f16)0.f;
        if (bok) bf = *(const v8h*)(bp + ich * 32);
        acc[0] = __builtin_amdgcn_mfma_f32_16x16x32_f16(a0, bf, acc[0], 0, 0, 0);
        acc[1] = __builtin_amdgcn_mfma_f32_16x16x32_f16(a1, bf, acc[1], 0, 0, 0);
        acc[2] = __builtin_amdgcn_mfma_f32_16x16x32_f16(a2, bf, acc[2], 0, 0, 0);
        acc[3] = __builtin_amdgcn_mfma_f32_16x16x32_f16(a3, bf, acc[3], 0, 0, 0);
      }
    }
  }
  #pragma unroll
  for (int mt = 0; mt < 4; mt++) {
    int oc0 = ocg * 64 + mt * 16 + quad * 4;
    float4 bb = *(const float4*)(b3 + oc0);
    float rv[4];
    #pragma unroll
    for (int r = 0; r < 4; r++) {
      float v = acc[mt][r] + ((const float*)&bb)[r];
      rv[r] = v > 0.f ? v : 0.f;
    }
    #pragma unroll
    for (int r = 0; r < 4; r++)
      zout[(((long)(b * 128 + oc0 + r) * 64 + oh) * 64) + ow] = rv[r];
    h4 pk;
    #pragma unroll
    for (int r = 0; r < 4; r++) pk[r] = (f16)rv[r];
    *(h4*)(nhwc + (((long)(b * 64 + oh) * 64 + ow) * 128) + oc0) = pk;
  }
}

// ---------------- local correlation via MFMA: K=13, C=128 ----------------
__global__ __launch_bounds__(256) void corr_m(const f16* __restrict__ zt,
    const f16* __restrict__ zt1, float* __restrict__ corr, float* __restrict__ part)
{
  const int h = blockIdx.x, b = blockIdx.y;
  const int lane = threadIdx.x & 63, wv = threadIdx.x >> 6;
  const int n15 = lane & 15, quad = lane >> 4;
  const int w0 = wv * 16;
  __shared__ float sC[64][17];

  const f16* arow = zt + (((long)(b * 64 + h) * 64 + (w0 + n15)) * 128) + quad * 8;
  v8h A[4];
  #pragma unroll
  for (int ks = 0; ks < 4; ks++) A[ks] = *(const v8h*)(arow + ks * 32);

  float* cb = corr + (long)b * 169 * 4096 + h * 64;

  const int q4r0 = quad * 4;
  const int wq0 = w0 - 6 + n15;
  const int wq1 = w0 + 10 + n15;
  const bool ok0 = (unsigned)wq0 < 64u;
  const bool ok1 = (unsigned)wq1 < 64u;

  for (int ki = 0; ki < 13; ki++) {
    int row = h + ki - 6;
    bool rok = (unsigned)row < 64u;
    v4f acc0 = {}, acc1 = {};
    if (rok) {
      const f16* brow = zt1 + ((long)(b * 64 + row) * 64) * 128;
      const f16* bp0 = brow + (long)wq0 * 128 + quad * 8;
      const f16* bp1 = brow + (long)wq1 * 128 + quad * 8;
      #pragma unroll
      for (int ks = 0; ks < 4; ks++) {
        v8h b0, b1;
        #pragma unroll
        for (int k = 0; k < 8; k++) { b0[k] = (f16)0.f; b1[k] = (f16)0.f; }
        if (ok0) b0 = *(const v8h*)(bp0 + ks * 32);
        if (ok1) b1 = *(const v8h*)(bp1 + ks * 32);
        acc0 = __builtin_amdgcn_mfma_f32_16x16x32_f16(A[ks], b0, acc0, 0, 0, 0);
        acc1 = __builtin_amdgcn_mfma_f32_16x16x32_f16(A[ks], b1, acc1, 0, 0, 0);
      }
    }
    __syncthreads();
    #pragma unroll
    for (int r = 0; r < 4; r++) {
      int q4r = q4r0 + r;
      int w = w0 + q4r;
      int kj0 = n15 - q4r;
      if (kj0 >= 0 && kj0 < 13) sC[w][kj0] = acc0[r] * INV_SQRT_C;
      int kj1 = kj0 + 16;
      if (kj1 < 13) sC[w][kj1] = acc1[r] * INV_SQRT_C;
    }
    __syncthreads();
    for (int idx = threadIdx.x; idx < 832; idx += 256) {
      int w = idx & 63, kj = idx >> 6;
      float v = sC[w][kj];
      cb[(long)(ki * 13 + kj) * 4096 + w] = v;
      #pragma unroll
      for (int off = 32; off > 0; off >>= 1) v += __shfl_down(v, off, 64);
      if (lane == 0) part[(long)(ki * 13 + kj) * 2048 + b * 64 + h] = v;
    }
  }
}

// ---------------- h_t: reduce partial row sums over h ----------------
__global__ __launch_bounds__(256) void ht2_k(const float* __restrict__ part,
                                             float* __restrict__ ht)
{
  int o = blockIdx.x;
  int t = threadIdx.x;
  int b = t >> 3, s = t & 7;
  const float* p = part + (long)o * 2048 + b * 64 + s * 8;
  float v = 0.f;
  #pragma unroll
  for (int i = 0; i < 8; i++) v += p[i];
  #pragma unroll
  for (int off = 4; off > 0; off >>= 1) v += __shfl_down(v, off, 8);
  if (s == 0) ht[b * 169 + o] = v * (1.f / 4096.f);
}

// ---------------- pred: h_t @ w_head.T + b_head ----------------
__global__ void pred_k(const float* __restrict__ ht, const float* __restrict__ wh,
                       const float* __restrict__ bh, float* __restrict__ pred)
{
  int t = threadIdx.x;
  int b = t >> 1, j = t & 1;
  float s = bh[j];
  for (int o = 0; o < 169; o++) s = fmaf(ht[b * 169 + o], wh[j * 169 + o], s);
  pred[b * 2 + j] = s;
}

extern "C" void kernel_launch(void* const* d_in, const int* in_sizes, int n_in,
                              void* d_out, int out_size, void* d_ws, size_t ws_size,
                              hipStream_t stream)
{
  (void)in_sizes; (void)n_in; (void)out_size; (void)ws_size;
  const float* img_t  = (const float*)d_in[0];
  const float* img_t1 = (const float*)d_in[1];
  const float* w1 = (const float*)d_in[2];
  const float* b1 = (const float*)d_in[3];
  const float* w2 = (const float*)d_in[4];
  const float* b2 = (const float*)d_in[5];
  const float* w3 = (const float*)d_in[6];
  const float* b3 = (const float*)d_in[7];
  const float* wh = (const float*)d_in[8];
  const float* bh = (const float*)d_in[9];
  float* out = (float*)d_out;

  // workspace layout (fp16 intermediates)
  char* ws = (char*)d_ws;
  f16* bufB = (f16*)ws;                       // conv2 out NHWC: 32*128*128*64*2 = 64 MiB
  f16* nhT  = (f16*)(ws + 67108864L);         // z_t  NHWC fp16: 32 MiB
  f16* nhT1 = (f16*)(ws + 100663296L);        // z_t1 NHWC fp16: 32 MiB
  float* part = (float*)(ws + 134217728L);    // 169*2048*4 = 1.38 MiB

  const long OUT_ZT   = 64;
  const long OUT_ZT1  = OUT_ZT + 16777216L;
  const long OUT_CORR = OUT_ZT1 + 16777216L;
  const long OUT_HT   = OUT_CORR + 22151168L;

  // transposed weights live in the (not-yet-written) corr region of d_out;
  // corr_m fully overwrites this region afterwards.
  f16* wT2 = (f16*)(out + OUT_CORR);          // 18432 f16 = 36 KiB
  f16* wT3 = wT2 + 18432;                     // 73728 f16 = 144 KiB

  wt2_k<<<72, 256, 0, stream>>>(w2, wT2);
  wt3_k<<<288, 256, 0, stream>>>(w3, wT3);

  for (int img = 0; img < 2; img++) {
    const float* src = img ? img_t1 : img_t;
    float* zdst = out + (img ? OUT_ZT1 : OUT_ZT);
    f16* nh = img ? nhT1 : nhT;
    conv12_m<<<dim3(128, 2, 32), 256, 0, stream>>>(src, w1, b1, wT2, b2, bufB);
    conv3_m<<<dim3(64, 32, 2), 256, 0, stream>>>(bufB, wT3, b3, zdst, nh);
  }
  corr_m<<<dim3(64, 32), 256, 0, stream>>>(nhT, nhT1, out + OUT_CORR, part);
  ht2_k<<<169, 256, 0, stream>>>(part, out + OUT_HT);
  pred_k<<<1, 64, 0, stream>>>(out + OUT_HT, wh, bh, out);
}

// Round 3
// 775.371 us; speedup vs baseline: 1.2535x; 1.1099x over previous
//
#include <hip/hip_runtime.h>

typedef _Float16 f16;
typedef _Float16 h4 __attribute__((ext_vector_type(4)));
typedef _Float16 v8h __attribute__((ext_vector_type(8)));
typedef _Float16 h8 __attribute__((ext_vector_type(8)));
typedef float v4f __attribute__((ext_vector_type(4)));

#define INV_SQRT_C 0.08838834764831845f

// ---------------- weight transforms ----------------
// wT1: f16[64][32]. rows 0-31: A[oc][k], k=quad*8+j -> (c=quad, khkw=j) for quad<3, 0 for quad3.
// rows 32-63: khkw=8 tap: A2[oc][k] = k<3 ? w1[oc][c=k][2][2] : 0.
__global__ void wt1_k(const float* __restrict__ w1, f16* __restrict__ wT)
{
  int idx = blockIdx.x * 256 + threadIdx.x;   // 2048
  int k = idx & 31, row = idx >> 5;
  float v = 0.f;
  if (row < 32) {
    int oc = row, q = k >> 3, j = k & 7;
    if (q < 3) v = w1[(oc * 3 + q) * 9 + j];
  } else {
    int oc = row - 32;
    if (k < 3) v = w1[(oc * 3 + k) * 9 + 8];
  }
  wT[idx] = (f16)v;
}

__global__ void wt2_k(const float* __restrict__ w2, f16* __restrict__ wT)
{
  int idx = blockIdx.x * 256 + threadIdx.x;          // 18432
  int ic = idx & 31, oc = (idx >> 5) & 63, khkw = idx >> 11;
  wT[idx] = (f16)w2[(oc * 32 + ic) * 9 + khkw];
}

__global__ void wt3_k(const float* __restrict__ w3, f16* __restrict__ wT)
{
  int idx = blockIdx.x * 256 + threadIdx.x;          // 73728
  int ic5 = idx & 31, oc = (idx >> 5) & 127, ch = idx >> 12;
  int khkw = ch >> 1, ich = ch & 1;
  int ic = ich * 32 + ic5;
  wT[idx] = (f16)w3[(oc * 64 + ic) * 9 + khkw];
}

// ---------------- fused conv1 (MFMA im2col) + conv2 MFMA ----------------
// grid (128 oh, 2 ow-half, 32 b); block 256 = 4 waves.
// conv1: 387 pixels (3 rows x 129 cols) as 25 groups of 16 columns; per group:
// 8 ds_read_u16 (B1, compile-time imms) + 1 ds_read_b64 (B2, tap 9) + 4 MFMA.
// sA writes/reads XOR-swizzled with s=(ci>>1)&3 (16B-chunk granularity).
__global__ __launch_bounds__(256, 4) void conv12_m(const float* __restrict__ img,
    const f16* __restrict__ wT1, const float* __restrict__ b1,
    const f16* __restrict__ wT2, const float* __restrict__ b2, f16* __restrict__ out)
{
  const int oh = blockIdx.x, g = blockIdx.y, b = blockIdx.z;
  const int tid = threadIdx.x;
  const int lane = tid & 63, wv = tid >> 6;
  const int n15 = lane & 15, quad = lane >> 4;

  __shared__ f16 sImgF[5][134][4];
  __shared__ f16 sA[3 * 132 * 32];

  const int OW0 = g * 64;
  const int ibase = 2 * OW0 - 2;   // img col of sImgF col 0
  const int ihb = 2 * oh - 2;      // img row of sImgF row 0
  const float* imgb = img + (long)b * 3 * 65536;

  // stage img tile fp16: 3 ch x 5 rows x 134 cols (zero-padded), + zero c=3 plane
  for (int idx = tid; idx < 2010; idx += 256) {
    int col = idx % 134; int t2 = idx / 134; int r = t2 % 5; int c = t2 / 5;
    int ih = ihb + r, iw = ibase + col;
    f16 v = (f16)0.f;
    if ((unsigned)ih < 256u && (unsigned)iw < 256u) v = (f16)imgb[c * 65536 + ih * 256 + iw];
    sImgF[r][col][c] = v;
  }
  for (int idx = tid; idx < 670; idx += 256) {
    int col = idx % 134, r = idx / 134;
    sImgF[r][col][3] = (f16)0.f;
  }
  __syncthreads();

  // conv1 A-frags + biases (hoisted)
  v8h a0 = *(const v8h*)(wT1 + n15 * 32 + quad * 8);
  v8h a1 = *(const v8h*)(wT1 + (16 + n15) * 32 + quad * 8);
  v8h a2 = *(const v8h*)(wT1 + (32 + n15) * 32 + quad * 8);
  v8h a3 = *(const v8h*)(wT1 + (48 + n15) * 32 + quad * 8);
  float4 bb0 = *(const float4*)(b1 + quad * 4);
  float4 bb1 = *(const float4*)(b1 + 16 + quad * 4);

  for (int grp = wv; grp < 25; grp += 4) {
    int p = grp * 16 + n15;
    bool pv = p < 387;
    int pc = pv ? p : 386;
    int yr = pc >= 258 ? 2 : (pc >= 129 ? 1 : 0);
    int ci = pc - yr * 129;
    const f16* sp = &sImgF[yr][ci][0] + quad;
    v8h B1;
    #pragma unroll
    for (int j = 0; j < 8; j++)
      B1[j] = sp[(j / 3) * 536 + (j % 3) * 4];   // sImgF[yr+j/3][ci+j%3][quad]
    h4 t = *(const h4*)(&sImgF[yr + 2][ci + 2][0]);
    v8h B2;
    B2[0] = t[0]; B2[1] = t[1]; B2[2] = t[2]; B2[3] = t[3];
    B2[4] = t[0]; B2[5] = t[1]; B2[6] = t[2]; B2[7] = t[3];
    v4f acc0 = {}, acc1 = {};
    acc0 = __builtin_amdgcn_mfma_f32_16x16x32_f16(a0, B1, acc0, 0, 0, 0);
    acc1 = __builtin_amdgcn_mfma_f32_16x16x32_f16(a1, B1, acc1, 0, 0, 0);
    acc0 = __builtin_amdgcn_mfma_f32_16x16x32_f16(a2, B2, acc0, 0, 0, 0);
    acc1 = __builtin_amdgcn_mfma_f32_16x16x32_f16(a3, B2, acc1, 0, 0, 0);
    // epilogue: oc = quad*4+r (+16), pixel (yr, ci); zero if conv1 output OOB
    int y = 2 * oh - 1 + yr;
    int iw = ibase + 1 + ci;
    bool valid = pv && ((unsigned)y < 256u) && ((unsigned)iw < 256u);
    int s = (ci >> 1) & 3;
    f16* base = &sA[(yr * 132 + ci) * 32];
    h4 pk0, pk1;
    #pragma unroll
    for (int r = 0; r < 4; r++) {
      float v0 = acc0[r] + ((const float*)&bb0)[r];
      float v1 = acc1[r] + ((const float*)&bb1)[r];
      pk0[r] = (f16)((valid && v0 > 0.f) ? v0 : 0.f);
      pk1[r] = (f16)((valid && v1 > 0.f) ? v1 : 0.f);
    }
    if (pv) {
      *(h4*)(base + (((quad >> 1) ^ s) << 3) + ((quad & 1) << 2)) = pk0;
      *(h4*)(base + ((((quad >> 1) + 2) ^ s) << 3) + ((quad & 1) << 2)) = pk1;
    }
  }
  __syncthreads();

  // conv2 MFMA from LDS
  v4f acc[4] = {};
  for (int kh = 0; kh < 3; kh++) {
    for (int kw = 0; kw < 3; kw++) {
      int khkw = kh * 3 + kw;
      const f16* wp = wT2 + khkw * 2048 + n15 * 32 + quad * 8;
      v8h w0 = *(const v8h*)(wp);
      v8h w1v = *(const v8h*)(wp + 512);
      v8h w2v = *(const v8h*)(wp + 1024);
      v8h w3v = *(const v8h*)(wp + 1536);
      int ci = 32 * wv + 2 * n15 + kw;
      v8h bf = *(const v8h*)&sA[(kh * 132 + ci) * 32 + ((quad ^ ((ci >> 1) & 3)) << 3)];
      acc[0] = __builtin_amdgcn_mfma_f32_16x16x32_f16(w0, bf, acc[0], 0, 0, 0);
      acc[1] = __builtin_amdgcn_mfma_f32_16x16x32_f16(w1v, bf, acc[1], 0, 0, 0);
      acc[2] = __builtin_amdgcn_mfma_f32_16x16x32_f16(w2v, bf, acc[2], 0, 0, 0);
      acc[3] = __builtin_amdgcn_mfma_f32_16x16x32_f16(w3v, bf, acc[3], 0, 0, 0);
    }
  }
  const int ow = OW0 + wv * 16 + n15;
  #pragma unroll
  for (int mt = 0; mt < 4; mt++) {
    int oc0 = mt * 16 + quad * 4;
    float4 bb = *(const float4*)(b2 + oc0);
    h4 pk;
    #pragma unroll
    for (int r = 0; r < 4; r++) {
      float v = acc[mt][r] + ((const float*)&bb)[r];
      pk[r] = (f16)(v > 0.f ? v : 0.f);
    }
    *(h4*)(out + (((long)(b * 128 + oh) * 128 + ow) * 64) + oc0) = pk;
  }
}

// ---------------- conv3 MFMA: 64->128, stride 2, out 64x64 ----------------
__global__ __launch_bounds__(256, 4) void conv3_m(const f16* __restrict__ in,
    const f16* __restrict__ wT, const float* __restrict__ b3,
    float* __restrict__ zout, f16* __restrict__ nhwc)
{
  const int oh = blockIdx.x, b = blockIdx.y, ocg = blockIdx.z;
  const int lane = threadIdx.x & 63, wv = threadIdx.x >> 6;
  const int n15 = lane & 15, quad = lane >> 4;
  const int ow = wv * 16 + n15;
  v4f acc[4] = {};
  const int ih0 = 2 * oh - 1;
  for (int kh = 0; kh < 3; kh++) {
    int ih = ih0 + kh;
    bool ihok = (unsigned)ih < 128u;
    const f16* inrow = in + ((long)(b * 128 + (ihok ? ih : 0))) * (128 * 64);
    for (int kw = 0; kw < 3; kw++) {
      int iw = 2 * ow + kw - 1;
      bool bok = ihok && (unsigned)iw < 128u;
      const f16* bp = inrow + iw * 64 + quad * 8;
      #pragma unroll
      for (int ich = 0; ich < 2; ich++) {
        int ch = (kh * 3 + kw) * 2 + ich;
        const f16* wp = wT + ((long)(ch * 128 + ocg * 64 + n15)) * 32 + quad * 8;
        v8h a0 = *(const v8h*)(wp);
        v8h a1 = *(const v8h*)(wp + 512);
        v8h a2 = *(const v8h*)(wp + 1024);
        v8h a3 = *(const v8h*)(wp + 1536);
        v8h bf;
        #pragma unroll
        for (int k = 0; k < 8; k++) bf[k] = (f16)0.f;
        if (bok) bf = *(const v8h*)(bp + ich * 32);
        acc[0] = __builtin_amdgcn_mfma_f32_16x16x32_f16(a0, bf, acc[0], 0, 0, 0);
        acc[1] = __builtin_amdgcn_mfma_f32_16x16x32_f16(a1, bf, acc[1], 0, 0, 0);
        acc[2] = __builtin_amdgcn_mfma_f32_16x16x32_f16(a2, bf, acc[2], 0, 0, 0);
        acc[3] = __builtin_amdgcn_mfma_f32_16x16x32_f16(a3, bf, acc[3], 0, 0, 0);
      }
    }
  }
  #pragma unroll
  for (int mt = 0; mt < 4; mt++) {
    int oc0 = ocg * 64 + mt * 16 + quad * 4;
    float4 bb = *(const float4*)(b3 + oc0);
    float rv[4];
    #pragma unroll
    for (int r = 0; r < 4; r++) {
      float v = acc[mt][r] + ((const float*)&bb)[r];
      rv[r] = v > 0.f ? v : 0.f;
    }
    #pragma unroll
    for (int r = 0; r < 4; r++)
      zout[(((long)(b * 128 + oc0 + r) * 64 + oh) * 64) + ow] = rv[r];
    h4 pk;
    #pragma unroll
    for (int r = 0; r < 4; r++) pk[r] = (f16)rv[r];
    *(h4*)(nhwc + (((long)(b * 64 + oh) * 64 + ow) * 128) + oc0) = pk;
  }
}

// ---------------- local correlation via MFMA: K=13, C=128 ----------------
__global__ __launch_bounds__(256) void corr_m(const f16* __restrict__ zt,
    const f16* __restrict__ zt1, float* __restrict__ corr, float* __restrict__ part)
{
  const int h = blockIdx.x, b = blockIdx.y;
  const int lane = threadIdx.x & 63, wv = threadIdx.x >> 6;
  const int n15 = lane & 15, quad = lane >> 4;
  const int w0 = wv * 16;
  __shared__ float sC[64][17];

  const f16* arow = zt + (((long)(b * 64 + h) * 64 + (w0 + n15)) * 128) + quad * 8;
  v8h A[4];
  #pragma unroll
  for (int ks = 0; ks < 4; ks++) A[ks] = *(const v8h*)(arow + ks * 32);

  float* cb = corr + (long)b * 169 * 4096 + h * 64;

  const int q4r0 = quad * 4;
  const int wq0 = w0 - 6 + n15;
  const int wq1 = w0 + 10 + n15;
  const bool ok0 = (unsigned)wq0 < 64u;
  const bool ok1 = (unsigned)wq1 < 64u;

  for (int ki = 0; ki < 13; ki++) {
    int row = h + ki - 6;
    bool rok = (unsigned)row < 64u;
    v4f acc0 = {}, acc1 = {};
    if (rok) {
      const f16* brow = zt1 + ((long)(b * 64 + row) * 64) * 128;
      const f16* bp0 = brow + (long)wq0 * 128 + quad * 8;
      const f16* bp1 = brow + (long)wq1 * 128 + quad * 8;
      #pragma unroll
      for (int ks = 0; ks < 4; ks++) {
        v8h b0, b1;
        #pragma unroll
        for (int k = 0; k < 8; k++) { b0[k] = (f16)0.f; b1[k] = (f16)0.f; }
        if (ok0) b0 = *(const v8h*)(bp0 + ks * 32);
        if (ok1) b1 = *(const v8h*)(bp1 + ks * 32);
        acc0 = __builtin_amdgcn_mfma_f32_16x16x32_f16(A[ks], b0, acc0, 0, 0, 0);
        acc1 = __builtin_amdgcn_mfma_f32_16x16x32_f16(A[ks], b1, acc1, 0, 0, 0);
      }
    }
    __syncthreads();
    #pragma unroll
    for (int r = 0; r < 4; r++) {
      int q4r = q4r0 + r;
      int w = w0 + q4r;
      int kj0 = n15 - q4r;
      if (kj0 >= 0 && kj0 < 13) sC[w][kj0] = acc0[r] * INV_SQRT_C;
      int kj1 = kj0 + 16;
      if (kj1 < 13) sC[w][kj1] = acc1[r] * INV_SQRT_C;
    }
    __syncthreads();
    for (int idx = threadIdx.x; idx < 832; idx += 256) {
      int w = idx & 63, kj = idx >> 6;
      float v = sC[w][kj];
      cb[(long)(ki * 13 + kj) * 4096 + w] = v;
      #pragma unroll
      for (int off = 32; off > 0; off >>= 1) v += __shfl_down(v, off, 64);
      if (lane == 0) part[(long)(ki * 13 + kj) * 2048 + b * 64 + h] = v;
    }
  }
}

// ---------------- h_t: reduce partial row sums over h ----------------
__global__ __launch_bounds__(256) void ht2_k(const float* __restrict__ part,
                                             float* __restrict__ ht)
{
  int o = blockIdx.x;
  int t = threadIdx.x;
  int b = t >> 3, s = t & 7;
  const float* p = part + (long)o * 2048 + b * 64 + s * 8;
  float v = 0.f;
  #pragma unroll
  for (int i = 0; i < 8; i++) v += p[i];
  #pragma unroll
  for (int off = 4; off > 0; off >>= 1) v += __shfl_down(v, off, 8);
  if (s == 0) ht[b * 169 + o] = v * (1.f / 4096.f);
}

// ---------------- pred: h_t @ w_head.T + b_head ----------------
__global__ void pred_k(const float* __restrict__ ht, const float* __restrict__ wh,
                       const float* __restrict__ bh, float* __restrict__ pred)
{
  int t = threadIdx.x;
  int b = t >> 1, j = t & 1;
  float s = bh[j];
  for (int o = 0; o < 169; o++) s = fmaf(ht[b * 169 + o], wh[j * 169 + o], s);
  pred[b * 2 + j] = s;
}

extern "C" void kernel_launch(void* const* d_in, const int* in_sizes, int n_in,
                              void* d_out, int out_size, void* d_ws, size_t ws_size,
                              hipStream_t stream)
{
  (void)in_sizes; (void)n_in; (void)out_size; (void)ws_size;
  const float* img_t  = (const float*)d_in[0];
  const float* img_t1 = (const float*)d_in[1];
  const float* w1 = (const float*)d_in[2];
  const float* b1 = (const float*)d_in[3];
  const float* w2 = (const float*)d_in[4];
  const float* b2 = (const float*)d_in[5];
  const float* w3 = (const float*)d_in[6];
  const float* b3 = (const float*)d_in[7];
  const float* wh = (const float*)d_in[8];
  const float* bh = (const float*)d_in[9];
  float* out = (float*)d_out;

  // workspace layout (fp16 intermediates)
  char* ws = (char*)d_ws;
  f16* bufB = (f16*)ws;                       // conv2 out NHWC: 64 MiB
  f16* nhT  = (f16*)(ws + 67108864L);         // z_t  NHWC fp16: 32 MiB
  f16* nhT1 = (f16*)(ws + 100663296L);        // z_t1 NHWC fp16: 32 MiB
  float* part = (float*)(ws + 134217728L);    // 169*2048*4 = 1.38 MiB

  const long OUT_ZT   = 64;
  const long OUT_ZT1  = OUT_ZT + 16777216L;
  const long OUT_CORR = OUT_ZT1 + 16777216L;
  const long OUT_HT   = OUT_CORR + 22151168L;

  // transposed weights live in the (not-yet-written) corr region of d_out;
  // corr_m fully overwrites this region afterwards.
  f16* wT1 = (f16*)(out + OUT_CORR);          // 2048  f16 =   4 KiB
  f16* wT2 = wT1 + 2048;                      // 18432 f16 =  36 KiB
  f16* wT3 = wT2 + 18432;                     // 73728 f16 = 144 KiB

  wt1_k<<<8, 256, 0, stream>>>(w1, wT1);
  wt2_k<<<72, 256, 0, stream>>>(w2, wT2);
  wt3_k<<<288, 256, 0, stream>>>(w3, wT3);

  for (int img = 0; img < 2; img++) {
    const float* src = img ? img_t1 : img_t;
    float* zdst = out + (img ? OUT_ZT1 : OUT_ZT);
    f16* nh = img ? nhT1 : nhT;
    conv12_m<<<dim3(128, 2, 32), 256, 0, stream>>>(src, wT1, b1, wT2, b2, bufB);
    conv3_m<<<dim3(64, 32, 2), 256, 0, stream>>>(bufB, wT3, b3, zdst, nh);
  }
  corr_m<<<dim3(64, 32), 256, 0, stream>>>(nhT, nhT1, out + OUT_CORR, part);
  ht2_k<<<169, 256, 0, stream>>>(part, out + OUT_HT);
  pred_k<<<1, 64, 0, stream>>>(out + OUT_HT, wh, bh, out);
}

// Round 5
// 747.760 us; speedup vs baseline: 1.2998x; 1.0369x over previous
//
#include <hip/hip_runtime.h>

typedef _Float16 f16;
typedef _Float16 h4 __attribute__((ext_vector_type(4)));
typedef _Float16 v8h __attribute__((ext_vector_type(8)));
typedef _Float16 h8 __attribute__((ext_vector_type(8)));
typedef float v4f __attribute__((ext_vector_type(4)));

#define INV_SQRT_C 0.08838834764831845f

// ---------------- weight transforms ----------------
__global__ void wt1_k(const float* __restrict__ w1, f16* __restrict__ wT)
{
  int idx = blockIdx.x * 256 + threadIdx.x;   // 2048
  int k = idx & 31, row = idx >> 5;
  float v = 0.f;
  if (row < 32) {
    int oc = row, q = k >> 3, j = k & 7;
    if (q < 3) v = w1[(oc * 3 + q) * 9 + j];
  } else {
    int oc = row - 32;
    if (k < 3) v = w1[(oc * 3 + k) * 9 + 8];
  }
  wT[idx] = (f16)v;
}

__global__ void wt2_k(const float* __restrict__ w2, f16* __restrict__ wT)
{
  int idx = blockIdx.x * 256 + threadIdx.x;          // 18432
  int ic = idx & 31, oc = (idx >> 5) & 63, khkw = idx >> 11;
  wT[idx] = (f16)w2[(oc * 32 + ic) * 9 + khkw];
}

__global__ void wt3_k(const float* __restrict__ w3, f16* __restrict__ wT)
{
  int idx = blockIdx.x * 256 + threadIdx.x;          // 73728
  int ic5 = idx & 31, oc = (idx >> 5) & 127, ch = idx >> 12;
  int khkw = ch >> 1, ich = ch & 1;
  int ic = ich * 32 + ic5;
  wT[idx] = (f16)w3[(oc * 64 + ic) * 9 + khkw];
}

// ---------------- fused conv1 (MFMA im2col) + conv2 MFMA ----------------
// grid (128 oh, 2 ow-half, 64 bb); bb = img*32 + b. block 256 = 4 waves.
__global__ __launch_bounds__(256, 4) void conv12_m(const float* __restrict__ img_t,
    const float* __restrict__ img_t1,
    const f16* __restrict__ wT1, const float* __restrict__ b1,
    const f16* __restrict__ wT2, const float* __restrict__ b2, f16* __restrict__ out)
{
  const int oh = blockIdx.x, g = blockIdx.y, bb = blockIdx.z;
  const int tid = threadIdx.x;
  const int lane = tid & 63, wv = tid >> 6;
  const int n15 = lane & 15, quad = lane >> 4;

  __shared__ f16 sImgF[5][134][4];
  __shared__ f16 sA[3 * 132 * 32];

  const int OW0 = g * 64;
  const int ibase = 2 * OW0 - 2;
  const int ihb = 2 * oh - 2;
  const float* imgb = (bb < 32 ? img_t : img_t1) + (long)(bb & 31) * 3 * 65536;

  for (int idx = tid; idx < 2010; idx += 256) {
    int col = idx % 134; int t2 = idx / 134; int r = t2 % 5; int c = t2 / 5;
    int ih = ihb + r, iw = ibase + col;
    f16 v = (f16)0.f;
    if ((unsigned)ih < 256u && (unsigned)iw < 256u) v = (f16)imgb[c * 65536 + ih * 256 + iw];
    sImgF[r][col][c] = v;
  }
  for (int idx = tid; idx < 670; idx += 256) {
    int col = idx % 134, r = idx / 134;
    sImgF[r][col][3] = (f16)0.f;
  }
  __syncthreads();

  v8h a0 = *(const v8h*)(wT1 + n15 * 32 + quad * 8);
  v8h a1 = *(const v8h*)(wT1 + (16 + n15) * 32 + quad * 8);
  v8h a2 = *(const v8h*)(wT1 + (32 + n15) * 32 + quad * 8);
  v8h a3 = *(const v8h*)(wT1 + (48 + n15) * 32 + quad * 8);
  float4 bb0 = *(const float4*)(b1 + quad * 4);
  float4 bb1 = *(const float4*)(b1 + 16 + quad * 4);

  for (int grp = wv; grp < 25; grp += 4) {
    int p = grp * 16 + n15;
    bool pv = p < 387;
    int pc = pv ? p : 386;
    int yr = pc >= 258 ? 2 : (pc >= 129 ? 1 : 0);
    int ci = pc - yr * 129;
    const f16* sp = &sImgF[yr][ci][0] + quad;
    v8h B1;
    #pragma unroll
    for (int j = 0; j < 8; j++)
      B1[j] = sp[(j / 3) * 536 + (j % 3) * 4];
    h4 t = *(const h4*)(&sImgF[yr + 2][ci + 2][0]);
    v8h B2;
    B2[0] = t[0]; B2[1] = t[1]; B2[2] = t[2]; B2[3] = t[3];
    B2[4] = t[0]; B2[5] = t[1]; B2[6] = t[2]; B2[7] = t[3];
    v4f acc0 = {}, acc1 = {};
    acc0 = __builtin_amdgcn_mfma_f32_16x16x32_f16(a0, B1, acc0, 0, 0, 0);
    acc1 = __builtin_amdgcn_mfma_f32_16x16x32_f16(a1, B1, acc1, 0, 0, 0);
    acc0 = __builtin_amdgcn_mfma_f32_16x16x32_f16(a2, B2, acc0, 0, 0, 0);
    acc1 = __builtin_amdgcn_mfma_f32_16x16x32_f16(a3, B2, acc1, 0, 0, 0);
    int y = 2 * oh - 1 + yr;
    int iw = ibase + 1 + ci;
    bool valid = pv && ((unsigned)y < 256u) && ((unsigned)iw < 256u);
    int s = (ci >> 1) & 3;
    f16* base = &sA[(yr * 132 + ci) * 32];
    h4 pk0, pk1;
    #pragma unroll
    for (int r = 0; r < 4; r++) {
      float v0 = acc0[r] + ((const float*)&bb0)[r];
      float v1 = acc1[r] + ((const float*)&bb1)[r];
      pk0[r] = (f16)((valid && v0 > 0.f) ? v0 : 0.f);
      pk1[r] = (f16)((valid && v1 > 0.f) ? v1 : 0.f);
    }
    if (pv) {
      *(h4*)(base + (((quad >> 1) ^ s) << 3) + ((quad & 1) << 2)) = pk0;
      *(h4*)(base + ((((quad >> 1) + 2) ^ s) << 3) + ((quad & 1) << 2)) = pk1;
    }
  }
  __syncthreads();

  v4f acc[4] = {};
  for (int kh = 0; kh < 3; kh++) {
    for (int kw = 0; kw < 3; kw++) {
      int khkw = kh * 3 + kw;
      const f16* wp = wT2 + khkw * 2048 + n15 * 32 + quad * 8;
      v8h w0 = *(const v8h*)(wp);
      v8h w1v = *(const v8h*)(wp + 512);
      v8h w2v = *(const v8h*)(wp + 1024);
      v8h w3v = *(const v8h*)(wp + 1536);
      int ci = 32 * wv + 2 * n15 + kw;
      v8h bf = *(const v8h*)&sA[(kh * 132 + ci) * 32 + ((quad ^ ((ci >> 1) & 3)) << 3)];
      acc[0] = __builtin_amdgcn_mfma_f32_16x16x32_f16(w0, bf, acc[0], 0, 0, 0);
      acc[1] = __builtin_amdgcn_mfma_f32_16x16x32_f16(w1v, bf, acc[1], 0, 0, 0);
      acc[2] = __builtin_amdgcn_mfma_f32_16x16x32_f16(w2v, bf, acc[2], 0, 0, 0);
      acc[3] = __builtin_amdgcn_mfma_f32_16x16x32_f16(w3v, bf, acc[3], 0, 0, 0);
    }
  }
  const int ow = OW0 + wv * 16 + n15;
  #pragma unroll
  for (int mt = 0; mt < 4; mt++) {
    int oc0 = mt * 16 + quad * 4;
    float4 bbv = *(const float4*)(b2 + oc0);
    h4 pk;
    #pragma unroll
    for (int r = 0; r < 4; r++) {
      float v = acc[mt][r] + ((const float*)&bbv)[r];
      pk[r] = (f16)(v > 0.f ? v : 0.f);
    }
    *(h4*)(out + (((long)(bb * 128 + oh) * 128 + ow) * 64) + oc0) = pk;
  }
}

// ---------------- conv3 MFMA v2: 64->128, stride 2, LDS-staged, all 128 oc ----------------
// grid (64 oh, 64 bb); block 256 = 4 waves; wave wv covers ow [wv*16, wv*16+16), all 128 oc.
// Input slab 3x128x64 fp16 staged in LDS, 16B chunks XOR-swizzled with (iw>>1)&7.
__global__ __launch_bounds__(256, 3) void conv3_m(const f16* __restrict__ in,
    const f16* __restrict__ wT, const float* __restrict__ b3,
    float* __restrict__ zbase, f16* __restrict__ nhbase)
{
  const int oh = blockIdx.x, bb = blockIdx.y;
  const int ib = bb >> 5, b = bb & 31;
  const int tid = threadIdx.x;
  const int lane = tid & 63, wv = tid >> 6;
  const int n15 = lane & 15, quad = lane >> 4;
  const int ow = wv * 16 + n15;

  __shared__ f16 sIn[3 * 128 * 64];

  const f16* inb = in + (long)bb * (128 * 128 * 64);
  const int ih0 = 2 * oh - 1;
  // stage 3 rows x 128 iw x 64 ch (3072 16B chunks), swizzled
  for (int idx = tid; idx < 3072; idx += 256) {
    int ck = idx & 7, iw = (idx >> 3) & 127, r = idx >> 10;
    int ih = ih0 + r;
    h8 v;
    #pragma unroll
    for (int e = 0; e < 8; e++) v[e] = (f16)0.f;
    if ((unsigned)ih < 128u) v = *(const h8*)(inb + ((long)(ih * 128 + iw)) * 64 + ck * 8);
    int sck = ck ^ ((iw >> 1) & 7);
    *(h8*)(&sIn[(r * 128 + iw) * 64 + sck * 8]) = v;
  }
  __syncthreads();

  v4f acc[8] = {};
  for (int kh = 0; kh < 3; kh++) {
    for (int kw = 0; kw < 3; kw++) {
      int iw = 2 * ow + kw - 1;
      bool bok = (unsigned)iw < 128u;
      int iwc = bok ? iw : 0;
      #pragma unroll
      for (int ich = 0; ich < 2; ich++) {
        int ch = (kh * 3 + kw) * 2 + ich;
        int ck = ich * 4 + quad;
        int sck = ck ^ ((iwc >> 1) & 7);
        v8h bf;
        #pragma unroll
        for (int e = 0; e < 8; e++) bf[e] = (f16)0.f;
        if (bok) bf = *(const v8h*)&sIn[(kh * 128 + iwc) * 64 + sck * 8];
        const f16* wp = wT + ((long)(ch * 128 + n15)) * 32 + quad * 8;
        #pragma unroll
        for (int mt = 0; mt < 8; mt++) {
          v8h a = *(const v8h*)(wp + mt * 512);
          acc[mt] = __builtin_amdgcn_mfma_f32_16x16x32_f16(a, bf, acc[mt], 0, 0, 0);
        }
      }
    }
  }

  float* zo = zbase + (long)ib * 16777216L;
  f16* nh = nhbase + (long)ib * 16777216L;
  #pragma unroll
  for (int mt = 0; mt < 8; mt++) {
    int oc0 = mt * 16 + quad * 4;
    float4 bbv = *(const float4*)(b3 + oc0);
    float rv[4];
    #pragma unroll
    for (int r = 0; r < 4; r++) {
      float v = acc[mt][r] + ((const float*)&bbv)[r];
      rv[r] = v > 0.f ? v : 0.f;
    }
    #pragma unroll
    for (int r = 0; r < 4; r++)
      zo[(((long)(b * 128 + oc0 + r) * 64 + oh) * 64) + ow] = rv[r];
    h4 pk;
    #pragma unroll
    for (int r = 0; r < 4; r++) pk[r] = (f16)rv[r];
    *(h4*)(nh + (((long)(b * 64 + oh) * 64 + ow) * 128) + oc0) = pk;
  }
}

// ---------------- local correlation via MFMA: K=13, C=128 ----------------
__global__ __launch_bounds__(256) void corr_m(const f16* __restrict__ zt,
    const f16* __restrict__ zt1, float* __restrict__ corr, float* __restrict__ part)
{
  const int h = blockIdx.x, b = blockIdx.y;
  const int lane = threadIdx.x & 63, wv = threadIdx.x >> 6;
  const int n15 = lane & 15, quad = lane >> 4;
  const int w0 = wv * 16;
  __shared__ float sC[64][17];

  const f16* arow = zt + (((long)(b * 64 + h) * 64 + (w0 + n15)) * 128) + quad * 8;
  v8h A[4];
  #pragma unroll
  for (int ks = 0; ks < 4; ks++) A[ks] = *(const v8h*)(arow + ks * 32);

  float* cb = corr + (long)b * 169 * 4096 + h * 64;

  const int q4r0 = quad * 4;
  const int wq0 = w0 - 6 + n15;
  const int wq1 = w0 + 10 + n15;
  const bool ok0 = (unsigned)wq0 < 64u;
  const bool ok1 = (unsigned)wq1 < 64u;

  for (int ki = 0; ki < 13; ki++) {
    int row = h + ki - 6;
    bool rok = (unsigned)row < 64u;
    v4f acc0 = {}, acc1 = {};
    if (rok) {
      const f16* brow = zt1 + ((long)(b * 64 + row) * 64) * 128;
      const f16* bp0 = brow + (long)wq0 * 128 + quad * 8;
      const f16* bp1 = brow + (long)wq1 * 128 + quad * 8;
      #pragma unroll
      for (int ks = 0; ks < 4; ks++) {
        v8h b0, b1;
        #pragma unroll
        for (int k = 0; k < 8; k++) { b0[k] = (f16)0.f; b1[k] = (f16)0.f; }
        if (ok0) b0 = *(const v8h*)(bp0 + ks * 32);
        if (ok1) b1 = *(const v8h*)(bp1 + ks * 32);
        acc0 = __builtin_amdgcn_mfma_f32_16x16x32_f16(A[ks], b0, acc0, 0, 0, 0);
        acc1 = __builtin_amdgcn_mfma_f32_16x16x32_f16(A[ks], b1, acc1, 0, 0, 0);
      }
    }
    __syncthreads();
    #pragma unroll
    for (int r = 0; r < 4; r++) {
      int q4r = q4r0 + r;
      int w = w0 + q4r;
      int kj0 = n15 - q4r;
      if (kj0 >= 0 && kj0 < 13) sC[w][kj0] = acc0[r] * INV_SQRT_C;
      int kj1 = kj0 + 16;
      if (kj1 < 13) sC[w][kj1] = acc1[r] * INV_SQRT_C;
    }
    __syncthreads();
    for (int idx = threadIdx.x; idx < 832; idx += 256) {
      int w = idx & 63, kj = idx >> 6;
      float v = sC[w][kj];
      cb[(long)(ki * 13 + kj) * 4096 + w] = v;
      #pragma unroll
      for (int off = 32; off > 0; off >>= 1) v += __shfl_down(v, off, 64);
      if (lane == 0) part[(long)(ki * 13 + kj) * 2048 + b * 64 + h] = v;
    }
  }
}

// ---------------- h_t: reduce partial row sums over h ----------------
__global__ __launch_bounds__(256) void ht2_k(const float* __restrict__ part,
                                             float* __restrict__ ht)
{
  int o = blockIdx.x;
  int t = threadIdx.x;
  int b = t >> 3, s = t & 7;
  const float* p = part + (long)o * 2048 + b * 64 + s * 8;
  float v = 0.f;
  #pragma unroll
  for (int i = 0; i < 8; i++) v += p[i];
  #pragma unroll
  for (int off = 4; off > 0; off >>= 1) v += __shfl_down(v, off, 8);
  if (s == 0) ht[b * 169 + o] = v * (1.f / 4096.f);
}

// ---------------- pred ----------------
__global__ void pred_k(const float* __restrict__ ht, const float* __restrict__ wh,
                       const float* __restrict__ bh, float* __restrict__ pred)
{
  int t = threadIdx.x;
  int b = t >> 1, j = t & 1;
  float s = bh[j];
  for (int o = 0; o < 169; o++) s = fmaf(ht[b * 169 + o], wh[j * 169 + o], s);
  pred[b * 2 + j] = s;
}

extern "C" void kernel_launch(void* const* d_in, const int* in_sizes, int n_in,
                              void* d_out, int out_size, void* d_ws, size_t ws_size,
                              hipStream_t stream)
{
  (void)in_sizes; (void)n_in; (void)out_size; (void)ws_size;
  const float* img_t  = (const float*)d_in[0];
  const float* img_t1 = (const float*)d_in[1];
  const float* w1 = (const float*)d_in[2];
  const float* b1 = (const float*)d_in[3];
  const float* w2 = (const float*)d_in[4];
  const float* b2 = (const float*)d_in[5];
  const float* w3 = (const float*)d_in[6];
  const float* b3 = (const float*)d_in[7];
  const float* wh = (const float*)d_in[8];
  const float* bh = (const float*)d_in[9];
  float* out = (float*)d_out;

  // workspace layout
  char* ws = (char*)d_ws;
  f16* bufB = (f16*)ws;                       // conv2 out NHWC, both imgs: 128 MiB
  f16* nhT  = (f16*)(ws + 134217728L);        // z_t NHWC fp16: 32 MiB (z_t1 contiguous after)
  float* part = (float*)(ws + 201326592L);    // 1.38 MiB

  const long OUT_ZT   = 64;
  const long OUT_ZT1  = OUT_ZT + 16777216L;
  const long OUT_CORR = OUT_ZT1 + 16777216L;
  const long OUT_HT   = OUT_CORR + 22151168L;

  // transposed weights live in the (not-yet-written) corr region of d_out;
  // corr_m fully overwrites this region afterwards.
  f16* wT1 = (f16*)(out + OUT_CORR);          // 2048  f16
  f16* wT2 = wT1 + 2048;                      // 18432 f16
  f16* wT3 = wT2 + 18432;                     // 73728 f16

  wt1_k<<<8, 256, 0, stream>>>(w1, wT1);
  wt2_k<<<72, 256, 0, stream>>>(w2, wT2);
  wt3_k<<<288, 256, 0, stream>>>(w3, wT3);

  conv12_m<<<dim3(128, 2, 64), 256, 0, stream>>>(img_t, img_t1, wT1, b1, wT2, b2, bufB);
  conv3_m<<<dim3(64, 64), 256, 0, stream>>>(bufB, wT3, b3, out + OUT_ZT, nhT);
  corr_m<<<dim3(64, 32), 256, 0, stream>>>(nhT, nhT + 16777216L, out + OUT_CORR, part);
  ht2_k<<<169, 256, 0, stream>>>(part, out + OUT_HT);
  pred_k<<<1, 64, 0, stream>>>(out + OUT_HT, wh, bh, out);
}